// Round 5
// baseline (109.918 us; speedup 1.0000x reference)
//
#include <hip/hip_runtime.h>
#include <hip/hip_cooperative_groups.h>
#include <math.h>

namespace cg = cooperative_groups;

#define NB 64      // batch
#define NN 256     // elements per batch
#define NPAIRS 32640.0f   // N*(N-1)/2
#define EPSF 1e-8f

// ws layout (floats): per-batch 16-float record at ws[b*16 + q]:
//   q: 0 rank, 1 ovl, 2 aln, 3 noise, 4 posmse, 5 iou, 6 layermse, 7 conf,
//      8 golden, 9 areaSum, 10 area2Sum, 11 cxSum, 12 cySum, 13 vc
// No ticket, no memset: grid.sync() (cooperative launch) provides the barrier.

// Single-wave (64-lane) sum; result valid on lane 0.
__device__ __forceinline__ float wave_sum(float v) {
    #pragma unroll
    for (int off = 32; off > 0; off >>= 1) v += __shfl_down(v, off, 64);
    return v;
}

// One block per batch (64 blocks), 512 threads = 8 waves.
// Thread t: element i = t & 255, half = t >> 8. half 0 -> dd 1..64 + all duties;
// half 1 -> dd 65..128 (dd=128 only for i<128).
__global__ __launch_bounds__(512) void loss_coop(
    const float* __restrict__ pn, const float* __restrict__ tn,
    const float* __restrict__ pl, const float* __restrict__ tl,
    const float* __restrict__ mask, float* __restrict__ ws,
    float* __restrict__ out)
{
    // packed pair fields: sA = {x1, y1, x2, y2}, sB = {cx, cy, area, p_layer},
    // sC = {t_layer, m}
    __shared__ float4 sA[NN], sB[NN];
    __shared__ float2 sC[NN];
    __shared__ float sred[14 * 8];

    const int b    = blockIdx.x;        // batch
    const int tid  = threadIdx.x;       // 0..511
    const int i    = tid & 255;         // element within batch
    const int half = tid >> 8;          // 0 or 1
    const int e    = b * NN + i;
    const float m  = mask[e];

    // vectorized row loads (rows are 24B-aligned -> float2 ok)
    const float2* pl2 = (const float2*)pl;
    const float2* tl2 = (const float2*)tl;
    const int r2 = e * 3;
    const float2 pla = pl2[r2 + 0], plb = pl2[r2 + 1], plc = pl2[r2 + 2];
    const float2 tlc = tl2[r2 + 2];

    const float p0 = pla.x * m, p1 = pla.y * m,
                p2 = plb.x * m, p3 = plb.y * m,
                p4 = plc.x * m, p5 = plc.y * m;
    const float t4 = tlc.x * m, t5 = tlc.y * m;

    const float x2v = p0 + p2, y2v = p1 + p3;
    const float areav = p2 * p3;
    const float cxe = p0 + 0.5f * p2, cye = p1 + 0.5f * p3;

    if (half == 0) {
        sA[i] = make_float4(p0, p1, x2v, y2v);
        sB[i] = make_float4(cxe, cye, areav, p4);
        sC[i] = make_float2(t4, m);
    }
    __syncthreads();

    // ---------------- elementwise duties (half 0 only; half 1 adds zeros) ---
    float d_noise = 0.f, d_pos = 0.f, d_iou = 0.f, d_lm = 0.f, d_cf = 0.f,
          d_go = 0.f, d_ar = 0.f, d_a2 = 0.f, d_cx = 0.f, d_cy = 0.f, d_vc = 0.f;
    if (half == 0) {
        // noise SmoothL1
        const float2* pn2 = (const float2*)pn;
        const float2* tn2 = (const float2*)tn;
        float noise = 0.f;
        #pragma unroll
        for (int k = 0; k < 3; ++k) {
            float2 a = pn2[r2 + k], bb = tn2[r2 + k];
            float d0 = fabsf(a.x * m - bb.x * m);
            float d1 = fabsf(a.y * m - bb.y * m);
            noise += (d0 < 1.f) ? 0.5f * d0 * d0 : d0 - 0.5f;
            noise += (d1 < 1.f) ? 0.5f * d1 * d1 : d1 - 0.5f;
        }
        d_noise = noise;
        // position MSE + IoU
        const float2 tla = tl2[r2 + 0], tlb = tl2[r2 + 1];
        const float t0 = tla.x * m, t1 = tla.y * m,
                    t2 = tlb.x * m, t3 = tlb.y * m;
        d_pos = (p0 - t0) * (p0 - t0) + (p1 - t1) * (p1 - t1)
              + (p2 - t2) * (p2 - t2) + (p3 - t3) * (p3 - t3);
        const float tx2 = t0 + t2, ty2 = t1 + t3;
        float iw = fmaxf(fminf(x2v, tx2) - fmaxf(p0, t0), 0.f);
        float ih = fmaxf(fminf(y2v, ty2) - fmaxf(p1, t1), 0.f);
        float inter = iw * ih;
        d_iou = 1.f - inter / (areav + t2 * t3 - inter + EPSF);
        d_lm  = (p4 - t4) * (p4 - t4);
        d_cf  = (p5 - t5) * (p5 - t5);
        d_go  = fabsf(p2 / (p3 + EPSF) - 1.618f);
        d_ar  = areav * m;
        d_a2  = d_ar * d_ar;
        d_cx  = cxe * m;
        d_cy  = cye * m;
        d_vc  = m;
    }

    // ---------------- pairwise terms: this half's 64-dd range ---------------
    float rank = 0.f, ovl = 0.f, aln = 0.f;
    const int dd0 = half * 64 + 1;
    #pragma unroll 8
    for (int k = 0; k < 64; ++k) {
        const int dd = dd0 + k;
        int j = (i + dd) & 255;
        if (dd == 128 && i >= 128) continue;   // dd=128 pairs counted once (i<j)
        float4 aj = sA[j];
        float4 bj = sB[j];
        float2 cj = sC[j];
        float pv = m * cj.y;
        // overlap (fast rcp: rel err ~1e-7, amortized over 2M pairs)
        float ow = fmaxf(fminf(x2v, aj.z) - fmaxf(p0, aj.x), 0.f);
        float oh = fmaxf(fminf(y2v, aj.w) - fmaxf(p1, aj.y), 0.f);
        ovl += ow * oh * pv * __builtin_amdgcn_rcpf(fminf(areav, bj.z) + EPSF);
        // alignment (6 edge types, dist<5 -> dist/5; /5 folded into 0.2f)
        float pen = 0.f, d;
        d = fabsf(p0  - aj.x); pen += (d < 5.f) ? d : 0.f;
        d = fabsf(x2v - aj.z); pen += (d < 5.f) ? d : 0.f;
        d = fabsf(p1  - aj.y); pen += (d < 5.f) ? d : 0.f;
        d = fabsf(y2v - aj.w); pen += (d < 5.f) ? d : 0.f;
        d = fabsf(cxe - bj.x); pen += (d < 5.f) ? d : 0.f;
        d = fabsf(cye - bj.y); pen += (d < 5.f) ? d : 0.f;
        aln += pen * (0.2f * pv);
        // ranking BCE, exact algebra: min( log1p(exp(-|z|)) + relu(z), 100 )
        bool ilt = (i < j);
        float dlo = ilt ? (bj.w - p4) : (p4 - bj.w);
        bool ylt  = ilt ? (t4 < cj.x) : (cj.x < t4);
        float z   = ylt ? -dlo : dlo;
        float sp  = __logf(1.f + __expf(-fabsf(z))) + fmaxf(z, 0.f);
        rank += fminf(sp, 100.f);
    }

    // ---------------- block reduce 14 sums, one barrier -------------------
    {
        float r[14] = {rank, ovl, aln, d_noise, d_pos, d_iou, d_lm, d_cf,
                       d_go, d_ar, d_a2, d_cx, d_cy, d_vc};
        const int w = tid >> 6;           // wave 0..7
        #pragma unroll
        for (int q = 0; q < 14; ++q) {
            float v = r[q];
            #pragma unroll
            for (int off = 32; off > 0; off >>= 1) v += __shfl_down(v, off, 64);
            if ((tid & 63) == 0) sred[q * 8 + w] = v;
        }
        __syncthreads();
        if (tid < 14) {
            float s = 0.f;
            #pragma unroll
            for (int ww = 0; ww < 8; ++ww) s += sred[tid * 8 + ww];
            ws[b * 16 + tid] = s;
        }
    }

    // ---------------- grid-wide barrier (cooperative) ----------------------
    cg::this_grid().sync();

    if (blockIdx.x != 0) return;
    const int t = tid;
    if (t >= 64) return;   // one wave finalizes (no barriers below)

    // per-batch records (NB == 64 == wave width): lane t = batch t
    float v_rank  = ws[t * 16 + 0];
    float v_ovl   = ws[t * 16 + 1];
    float v_aln   = ws[t * 16 + 2];
    float v_noise = ws[t * 16 + 3];
    float v_pos   = ws[t * 16 + 4];
    float v_iou   = ws[t * 16 + 5];
    float v_lm    = ws[t * 16 + 6];
    float v_cf    = ws[t * 16 + 7];
    float v_go    = ws[t * 16 + 8];
    float v_ar    = ws[t * 16 + 9];
    float a2      = ws[t * 16 + 10];
    float v_cx    = ws[t * 16 + 11];
    float v_cy    = ws[t * 16 + 12];
    float v_vc    = ws[t * 16 + 13];
    // per-row std, ddof=1
    float var   = (a2 - v_ar * v_ar * (1.f / 256.f)) * (1.f / 255.f);
    float v_std = sqrtf(fmaxf(var, 0.f));

    // faithful [B,B] balance broadcast: ocx[i,j] = sumcx[j]/(vc[i]+EPS)
    float inv = 1.f / (v_vc + EPSF);
    float v_bal = 0.f;
    for (int j = 0; j < NB; ++j) {
        float cxj = __shfl(v_cx, j, 64);
        float cyj = __shfl(v_cy, j, 64);
        v_bal += fabsf(cxj * inv - 512.f) * (1.f / 512.f)
               + fabsf(cyj * inv - 512.f) * (1.f / 512.f);
    }

    float S_noise = wave_sum(v_noise);
    float S_pos   = wave_sum(v_pos);
    float S_iou   = wave_sum(v_iou);
    float S_lm    = wave_sum(v_lm);
    float S_cf    = wave_sum(v_cf);
    float S_go    = wave_sum(v_go);
    float S_ar    = wave_sum(v_ar);
    float S_std   = wave_sum(v_std);
    float S_bal   = wave_sum(v_bal);
    float S_rank  = wave_sum(v_rank);
    float S_ovl   = wave_sum(v_ovl);
    float S_aln   = wave_sum(v_aln);

    if (t == 0) {
        const float BN = 64.f * 256.f;
        float noise_loss = S_noise / (BN * 6.f);
        float position   = S_pos / (BN * 4.f) + 0.5f * (S_iou / BN);
        float layer      = S_lm / BN + 0.3f * (S_rank / (64.f * NPAIRS));
        float conf       = S_cf / BN;
        float golden     = S_go / BN;
        float size_harm  = (S_std / 64.f) / (S_ar / BN + EPSF);
        float balance    = S_bal / 4096.f;
        float aes        = 0.1f * golden + 0.2f * size_harm + 0.15f * balance;
        float ovl        = S_ovl / (64.f * NPAIRS);
        float aln        = S_aln / (64.f * 6.f * NPAIRS);
        out[0] = noise_loss + position + 0.5f * layer + 0.3f * conf
               + 0.2f * aes + 0.8f * ovl + 0.4f * aln;
    }
}

extern "C" void kernel_launch(void* const* d_in, const int* in_sizes, int n_in,
                              void* d_out, int out_size, void* d_ws, size_t ws_size,
                              hipStream_t stream) {
    const float* pn   = (const float*)d_in[0];
    const float* tn   = (const float*)d_in[1];
    const float* pl   = (const float*)d_in[2];
    const float* tl   = (const float*)d_in[3];
    const float* mask = (const float*)d_in[4];
    float* ws  = (float*)d_ws;
    float* out = (float*)d_out;
    void* args[] = { (void*)&pn, (void*)&tn, (void*)&pl, (void*)&tl,
                     (void*)&mask, (void*)&ws, (void*)&out };
    hipLaunchCooperativeKernel((const void*)loss_coop, dim3(NB), dim3(512),
                               args, 0, stream);
}

// Round 6
// 74.131 us; speedup vs baseline: 1.4827x; 1.4827x over previous
//
#include <hip/hip_runtime.h>
#include <math.h>

#define NB 64      // batch
#define NN 256     // elements per batch
#define NPAIRS 32640.0f   // N*(N-1)/2
#define EPSF 1e-8f

// ws layout (floats):
//   per-batch  [11][64]   at 0   : 0 noise,1 posmse,2 iou,3 layermse,4 conf,
//                                  5 golden,6 areaSum,7 area2Sum,8 cxSum,9 cySum,10 vc
//   per-block  [256][4]   at 704 : packed {rank, overlap, align, 0} per block
//   tickets    at 16384 : master at +0; group g (g<8) at +16*(1+g)  (64B-separated)
//   (tickets zeroed by a 1 KiB hipMemsetAsync each launch)
#define PB(q) ((q) * 64)
#define PWBASE 704
#define TICKET_OFF 16384

// Single-wave (64-lane) sum; result valid on lane 0.
__device__ __forceinline__ float wave_sum(float v) {
    #pragma unroll
    for (int off = 32; off > 0; off >>= 1) v += __shfl_down(v, off, 64);
    return v;
}

// Three block-wide sums sharing one barrier pair (sred holds >=12 floats).
__device__ __forceinline__ void block_sum3(float a, float b, float c, float* sred,
                                           float& ra, float& rb, float& rc) {
    const int tid = threadIdx.x;
    #pragma unroll
    for (int off = 32; off > 0; off >>= 1) {
        a += __shfl_down(a, off, 64);
        b += __shfl_down(b, off, 64);
        c += __shfl_down(c, off, 64);
    }
    __syncthreads();
    if ((tid & 63) == 0) {
        const int w = tid >> 6;
        sred[w] = a; sred[4 + w] = b; sred[8 + w] = c;
    }
    __syncthreads();
    ra = sred[0] + sred[1] + sred[2]  + sred[3];
    rb = sred[4] + sred[5] + sred[6]  + sred[7];
    rc = sred[8] + sred[9] + sred[10] + sred[11];
}

// Six block-wide sums sharing ONE barrier pair (sred holds >=24 floats).
__device__ __forceinline__ void block_sum6(float a, float b, float c,
                                           float d, float e, float f, float* sred,
                                           float& ra, float& rb, float& rc,
                                           float& rd, float& re, float& rf) {
    const int tid = threadIdx.x;
    #pragma unroll
    for (int off = 32; off > 0; off >>= 1) {
        a += __shfl_down(a, off, 64);
        b += __shfl_down(b, off, 64);
        c += __shfl_down(c, off, 64);
        d += __shfl_down(d, off, 64);
        e += __shfl_down(e, off, 64);
        f += __shfl_down(f, off, 64);
    }
    __syncthreads();
    if ((tid & 63) == 0) {
        const int w = tid >> 6;
        sred[w] = a; sred[4 + w] = b; sred[8 + w] = c;
        sred[12 + w] = d; sred[16 + w] = e; sred[20 + w] = f;
    }
    __syncthreads();
    ra = sred[0]  + sred[1]  + sred[2]  + sred[3];
    rb = sred[4]  + sred[5]  + sred[6]  + sred[7];
    rc = sred[8]  + sred[9]  + sred[10] + sred[11];
    rd = sred[12] + sred[13] + sred[14] + sred[15];
    re = sred[16] + sred[17] + sred[18] + sred[19];
    rf = sred[20] + sred[21] + sred[22] + sred[23];
}

__device__ __forceinline__ float ws_cload(const float* p) {
    // agent-scope coherent load: reads the coherence point (XCD L2s not coherent)
    return __hip_atomic_load(p, __ATOMIC_RELAXED, __HIP_MEMORY_SCOPE_AGENT);
}

__device__ __forceinline__ void ws_cstore(float* p, float v) {
    // agent-scope write-through store: globally visible once vmcnt-retired,
    // WITHOUT a __threadfence/buffer_wbl2 L2-writeback walk
    __hip_atomic_store(p, v, __ATOMIC_RELAXED, __HIP_MEMORY_SCOPE_AGENT);
}

// grid = 256: 64 batches x 4 chunks of 32 pair-distances each. Fused final via
// hierarchical last-block ticket: coherent partial stores + s_waitcnt vmcnt(0)
// + relaxed group/master RMWs (no fence, no wbl2). Winner reads coherent loads.
__global__ __launch_bounds__(256) void loss_fused(
    const float* __restrict__ pn, const float* __restrict__ tn,
    const float* __restrict__ pl, const float* __restrict__ tl,
    const float* __restrict__ mask, float* __restrict__ ws,
    float* __restrict__ out)
{
    // packed pair fields: sA = {x1, y1, x2, y2}, sB = {cx, cy, area, p_layer},
    // sC = {t_layer, m}
    __shared__ float4 sA[NN], sB[NN];
    __shared__ float2 sC[NN];
    __shared__ float sred[24];
    __shared__ int winflag;

    const int b     = blockIdx.x >> 2;   // batch
    const int chunk = blockIdx.x & 3;    // pair-distance chunk / duty-triple chunk
    const int i     = threadIdx.x;       // element within batch
    const int e     = b * NN + i;
    const float m   = mask[e];

    // vectorized row loads (rows are 24B-aligned -> float2 ok)
    const float2* pl2 = (const float2*)pl;
    const float2* tl2 = (const float2*)tl;
    const int r2 = e * 3;
    const float2 pla = pl2[r2 + 0], plb = pl2[r2 + 1], plc = pl2[r2 + 2];
    const float2 tlc = tl2[r2 + 2];

    const float p0 = pla.x * m, p1 = pla.y * m,
                p2 = plb.x * m, p3 = plb.y * m,
                p4 = plc.x * m, p5 = plc.y * m;
    const float t4 = tlc.x * m, t5 = tlc.y * m;

    const float x2v = p0 + p2, y2v = p1 + p3;
    const float areav = p2 * p3;
    const float cxe = p0 + 0.5f * p2, cye = p1 + 0.5f * p3;

    sA[i] = make_float4(p0, p1, x2v, y2v);
    sB[i] = make_float4(cxe, cye, areav, p4);
    sC[i] = make_float2(t4, m);
    __syncthreads();

    // ---------------- elementwise duty triple for this chunk ----------------
    float dA = 0.f, dB = 0.f, dC = 0.f;
    switch (chunk) {
    case 0: {
        // noise SmoothL1 (only chunk-0 blocks touch pn/tn)
        const float2* pn2 = (const float2*)pn;
        const float2* tn2 = (const float2*)tn;
        float noise = 0.f;
        #pragma unroll
        for (int k = 0; k < 3; ++k) {
            float2 a = pn2[r2 + k], bb = tn2[r2 + k];
            float d0 = fabsf(a.x * m - bb.x * m);
            float d1 = fabsf(a.y * m - bb.y * m);
            noise += (d0 < 1.f) ? 0.5f * d0 * d0 : d0 - 0.5f;
            noise += (d1 < 1.f) ? 0.5f * d1 * d1 : d1 - 0.5f;
        }
        dA = noise;
        // position MSE + IoU (needs target box rows)
        const float2 tla = tl2[r2 + 0], tlb = tl2[r2 + 1];
        const float t0 = tla.x * m, t1 = tla.y * m,
                    t2 = tlb.x * m, t3 = tlb.y * m;
        dB = (p0 - t0) * (p0 - t0) + (p1 - t1) * (p1 - t1)
           + (p2 - t2) * (p2 - t2) + (p3 - t3) * (p3 - t3);
        const float tx2 = t0 + t2, ty2 = t1 + t3;
        float iw = fmaxf(fminf(x2v, tx2) - fmaxf(p0, t0), 0.f);
        float ih = fmaxf(fminf(y2v, ty2) - fmaxf(p1, t1), 0.f);
        float inter = iw * ih;
        dC = 1.f - inter / (areav + t2 * t3 - inter + EPSF);
        break; }
    case 1:
        dA = (p4 - t4) * (p4 - t4);
        dB = (p5 - t5) * (p5 - t5);
        dC = fabsf(p2 / (p3 + EPSF) - 1.618f);
        break;
    case 2:
        dA = areav * m;
        dB = dA * dA;
        dC = cxe * m;
        break;
    default:
        dA = cye * m;
        dB = m;
        dC = 0.f;
        break;
    }

    // ---------------- pairwise terms (this chunk's 32-dd range) -------------
    float rank = 0.f, ovl = 0.f, aln = 0.f;
    const int dd0 = chunk * 32 + 1;
    #pragma unroll 8
    for (int k = 0; k < 32; ++k) {
        const int dd = dd0 + k;
        int j = (i + dd) & 255;
        if (dd == 128 && i >= 128) continue;   // dd=128 pairs counted once (i<j)
        float4 aj = sA[j];
        float4 bj = sB[j];
        float2 cj = sC[j];
        float pv = m * cj.y;
        // overlap (fast rcp: rel err ~1e-7, amortized over 2M pairs)
        float ow = fmaxf(fminf(x2v, aj.z) - fmaxf(p0, aj.x), 0.f);
        float oh = fmaxf(fminf(y2v, aj.w) - fmaxf(p1, aj.y), 0.f);
        ovl += ow * oh * pv * __builtin_amdgcn_rcpf(fminf(areav, bj.z) + EPSF);
        // alignment (6 edge types, dist<5 -> dist/5; /5 folded into 0.2f)
        float pen = 0.f, d;
        d = fabsf(p0  - aj.x); pen += (d < 5.f) ? d : 0.f;
        d = fabsf(x2v - aj.z); pen += (d < 5.f) ? d : 0.f;
        d = fabsf(p1  - aj.y); pen += (d < 5.f) ? d : 0.f;
        d = fabsf(y2v - aj.w); pen += (d < 5.f) ? d : 0.f;
        d = fabsf(cxe - bj.x); pen += (d < 5.f) ? d : 0.f;
        d = fabsf(cye - bj.y); pen += (d < 5.f) ? d : 0.f;
        aln += pen * (0.2f * pv);
        // ranking BCE, exact algebra: min( log1p(exp(-|z|)) + relu(z), 100 )
        bool ilt = (i < j);
        float dlo = ilt ? (bj.w - p4) : (p4 - bj.w);
        bool ylt  = ilt ? (t4 < cj.x) : (cj.x < t4);
        float z   = ylt ? -dlo : dlo;
        float sp  = __logf(1.f + __expf(-fabsf(z))) + fmaxf(z, 0.f);
        rank += fminf(sp, 100.f);
    }

    // one barrier pair for all six reductions
    float sr, so, sa, s1, s2, s3;
    block_sum6(rank, ovl, aln, dA, dB, dC, sred, sr, so, sa, s1, s2, s3);

    if (i == 0) {
        // publish partials as agent-scope write-through stores (no fence needed)
        float* pw = ws + PWBASE + blockIdx.x * 4;
        ws_cstore(pw + 0, sr);
        ws_cstore(pw + 1, so);
        ws_cstore(pw + 2, sa);
        // duty slots: chunk c writes slots {3c, 3c+1, 3c+2} (chunk 3: 9, 10 only)
        const int base = chunk * 3;
        ws_cstore(ws + PB(base + 0) + b, s1);
        ws_cstore(ws + PB(base + 1) + b, s2);
        if (chunk != 3) ws_cstore(ws + PB(base + 2) + b, s3);
        // all publishes retired -> globally visible (write-through)
        asm volatile("s_waitcnt vmcnt(0)" ::: "memory");
        // hierarchical ticket: 8 group lines (32 blocks each) + master line
        int win = 0;
        unsigned gold = atomicAdd(
            (unsigned*)(ws + TICKET_OFF + 16 * (1 + (blockIdx.x >> 5))), 1u);
        if (gold == 31u) {
            unsigned mold = atomicAdd((unsigned*)(ws + TICKET_OFF), 1u);
            win = (mold == 7u) ? 1 : 0;
        }
        winflag = win;
    }
    __syncthreads();
    if (!winflag) return;

    // ================= winner block: final reduction =================
    const int t = i;

    // 256 packed pair-partials, one per thread (coherent reads)
    float v_rank, v_ovl, v_aln;
    {
        const float* p = ws + PWBASE + t * 4;
        v_rank = ws_cload(p + 0);
        v_ovl  = ws_cload(p + 1);
        v_aln  = ws_cload(p + 2);
    }
    float S_rank, S_ovl, S_aln;
    block_sum3(v_rank, v_ovl, v_aln, sred, S_rank, S_ovl, S_aln);

    if (t < 64) {
        float v_noise = ws_cload(ws + PB(0) + t);
        float v_pos   = ws_cload(ws + PB(1) + t);
        float v_iou   = ws_cload(ws + PB(2) + t);
        float v_lm    = ws_cload(ws + PB(3) + t);
        float v_cf    = ws_cload(ws + PB(4) + t);
        float v_go    = ws_cload(ws + PB(5) + t);
        float v_ar    = ws_cload(ws + PB(6) + t);
        float a2      = ws_cload(ws + PB(7) + t);
        float v_cx    = ws_cload(ws + PB(8) + t);
        float v_cy    = ws_cload(ws + PB(9) + t);
        float v_vc    = ws_cload(ws + PB(10) + t);
        // per-row std, ddof=1
        float var   = (a2 - v_ar * v_ar * (1.f / 256.f)) * (1.f / 255.f);
        float v_std = sqrtf(fmaxf(var, 0.f));

        // faithful [B,B] balance broadcast: ocx[i,j] = sumcx[j]/(vc[i]+EPS)
        float inv = 1.f / (v_vc + EPSF);
        float v_bal = 0.f;
        for (int j = 0; j < NB; ++j) {
            float cxj = __shfl(v_cx, j, 64);
            float cyj = __shfl(v_cy, j, 64);
            v_bal += fabsf(cxj * inv - 512.f) * (1.f / 512.f)
                   + fabsf(cyj * inv - 512.f) * (1.f / 512.f);
        }

        float S_noise = wave_sum(v_noise);
        float S_pos   = wave_sum(v_pos);
        float S_iou   = wave_sum(v_iou);
        float S_lm    = wave_sum(v_lm);
        float S_cf    = wave_sum(v_cf);
        float S_go    = wave_sum(v_go);
        float S_ar    = wave_sum(v_ar);
        float S_std   = wave_sum(v_std);
        float S_bal   = wave_sum(v_bal);

        if (t == 0) {
            const float BN = 64.f * 256.f;
            float noise_loss = S_noise / (BN * 6.f);
            float position   = S_pos / (BN * 4.f) + 0.5f * (S_iou / BN);
            float layer      = S_lm / BN + 0.3f * (S_rank / (64.f * NPAIRS));
            float conf       = S_cf / BN;
            float golden     = S_go / BN;
            float size_harm  = (S_std / 64.f) / (S_ar / BN + EPSF);
            float balance    = S_bal / 4096.f;
            float aes        = 0.1f * golden + 0.2f * size_harm + 0.15f * balance;
            float ovl        = S_ovl / (64.f * NPAIRS);
            float aln        = S_aln / (64.f * 6.f * NPAIRS);
            out[0] = noise_loss + position + 0.5f * layer + 0.3f * conf
                   + 0.2f * aes + 0.8f * ovl + 0.4f * aln;
        }
    }
}

extern "C" void kernel_launch(void* const* d_in, const int* in_sizes, int n_in,
                              void* d_out, int out_size, void* d_ws, size_t ws_size,
                              hipStream_t stream) {
    const float* pn   = (const float*)d_in[0];
    const float* tn   = (const float*)d_in[1];
    const float* pl   = (const float*)d_in[2];
    const float* tl   = (const float*)d_in[3];
    const float* mask = (const float*)d_in[4];
    float* ws  = (float*)d_ws;
    float* out = (float*)d_out;
    // zero the ticket lines (1 KiB; ws is re-poisoned by the harness each iteration)
    hipMemsetAsync((char*)d_ws + TICKET_OFF * sizeof(float), 0, 1024, stream);
    hipLaunchKernelGGL(loss_fused, dim3(256), dim3(256), 0, stream,
                       pn, tn, pl, tl, mask, ws, out);
}

// Round 7
// 73.121 us; speedup vs baseline: 1.5032x; 1.0138x over previous
//
#include <hip/hip_runtime.h>
#include <math.h>

#define NB 64      // batch
#define NN 256     // elements per batch
#define NPAIRS 32640.0f   // N*(N-1)/2
#define EPSF 1e-8f

// ws layout (floats):
//   per-batch  [11][64]   at 0   : 0 noise,1 posmse,2 iou,3 layermse,4 conf,
//                                  5 golden,6 areaSum,7 area2Sum,8 cxSum,9 cySum,10 vc
//   per-block  [256][4]   at 704 : packed {rank, overlap, align, 0} per block
// Tickets live in __device__ globals (zero at module load, self-resetting each
// iteration) -> NO memset dispatch, single kernel launch total.
#define PB(q) ((q) * 64)
#define PWBASE 704

struct __align__(64) PadCtr { unsigned v; unsigned pad[15]; };
__device__ PadCtr g_group[8];   // 32 blocks per group
__device__ PadCtr g_master;

// Single-wave (64-lane) sum; result valid on lane 0.
__device__ __forceinline__ float wave_sum(float v) {
    #pragma unroll
    for (int off = 32; off > 0; off >>= 1) v += __shfl_down(v, off, 64);
    return v;
}

// Three block-wide sums sharing one barrier pair (sred holds >=12 floats).
__device__ __forceinline__ void block_sum3(float a, float b, float c, float* sred,
                                           float& ra, float& rb, float& rc) {
    const int tid = threadIdx.x;
    #pragma unroll
    for (int off = 32; off > 0; off >>= 1) {
        a += __shfl_down(a, off, 64);
        b += __shfl_down(b, off, 64);
        c += __shfl_down(c, off, 64);
    }
    __syncthreads();
    if ((tid & 63) == 0) {
        const int w = tid >> 6;
        sred[w] = a; sred[4 + w] = b; sred[8 + w] = c;
    }
    __syncthreads();
    ra = sred[0] + sred[1] + sred[2]  + sred[3];
    rb = sred[4] + sred[5] + sred[6]  + sred[7];
    rc = sred[8] + sred[9] + sred[10] + sred[11];
}

// Six block-wide sums sharing ONE barrier pair (sred holds >=24 floats).
__device__ __forceinline__ void block_sum6(float a, float b, float c,
                                           float d, float e, float f, float* sred,
                                           float& ra, float& rb, float& rc,
                                           float& rd, float& re, float& rf) {
    const int tid = threadIdx.x;
    #pragma unroll
    for (int off = 32; off > 0; off >>= 1) {
        a += __shfl_down(a, off, 64);
        b += __shfl_down(b, off, 64);
        c += __shfl_down(c, off, 64);
        d += __shfl_down(d, off, 64);
        e += __shfl_down(e, off, 64);
        f += __shfl_down(f, off, 64);
    }
    __syncthreads();
    if ((tid & 63) == 0) {
        const int w = tid >> 6;
        sred[w] = a; sred[4 + w] = b; sred[8 + w] = c;
        sred[12 + w] = d; sred[16 + w] = e; sred[20 + w] = f;
    }
    __syncthreads();
    ra = sred[0]  + sred[1]  + sred[2]  + sred[3];
    rb = sred[4]  + sred[5]  + sred[6]  + sred[7];
    rc = sred[8]  + sred[9]  + sred[10] + sred[11];
    rd = sred[12] + sred[13] + sred[14] + sred[15];
    re = sred[16] + sred[17] + sred[18] + sred[19];
    rf = sred[20] + sred[21] + sred[22] + sred[23];
}

__device__ __forceinline__ float ws_cload(const float* p) {
    // agent-scope coherent load: reads the coherence point (XCD L2s not coherent)
    return __hip_atomic_load(p, __ATOMIC_RELAXED, __HIP_MEMORY_SCOPE_AGENT);
}

__device__ __forceinline__ void ws_cstore(float* p, float v) {
    // agent-scope write-through store: globally visible once vmcnt-retired,
    // WITHOUT a __threadfence/buffer_wbl2 L2-writeback walk
    __hip_atomic_store(p, v, __ATOMIC_RELAXED, __HIP_MEMORY_SCOPE_AGENT);
}

__device__ __forceinline__ unsigned ctr_add(unsigned* p) {
    return __hip_atomic_fetch_add(p, 1u, __ATOMIC_RELAXED,
                                  __HIP_MEMORY_SCOPE_AGENT);
}

__device__ __forceinline__ void ctr_reset(unsigned* p) {
    __hip_atomic_store(p, 0u, __ATOMIC_RELAXED, __HIP_MEMORY_SCOPE_AGENT);
}

// grid = 256: 64 batches x 4 chunks of 32 pair-distances each. Fused final via
// self-resetting hierarchical ticket in __device__ globals: coherent partial
// stores + s_waitcnt vmcnt(0) + relaxed group/master RMWs (no fence, no memset).
__global__ __launch_bounds__(256) void loss_fused(
    const float* __restrict__ pn, const float* __restrict__ tn,
    const float* __restrict__ pl, const float* __restrict__ tl,
    const float* __restrict__ mask, float* __restrict__ ws,
    float* __restrict__ out)
{
    // packed pair fields: sA = {x1, y1, x2, y2}, sB = {cx, cy, area, p_layer},
    // sC = {t_layer, m}
    __shared__ float4 sA[NN], sB[NN];
    __shared__ float2 sC[NN];
    __shared__ float sred[24];
    __shared__ int winflag;

    const int b     = blockIdx.x >> 2;   // batch
    const int chunk = blockIdx.x & 3;    // pair-distance chunk / duty-triple chunk
    const int i     = threadIdx.x;       // element within batch
    const int e     = b * NN + i;
    const float m   = mask[e];

    // vectorized row loads (rows are 24B-aligned -> float2 ok)
    const float2* pl2 = (const float2*)pl;
    const float2* tl2 = (const float2*)tl;
    const int r2 = e * 3;
    const float2 pla = pl2[r2 + 0], plb = pl2[r2 + 1], plc = pl2[r2 + 2];
    const float2 tlc = tl2[r2 + 2];

    const float p0 = pla.x * m, p1 = pla.y * m,
                p2 = plb.x * m, p3 = plb.y * m,
                p4 = plc.x * m, p5 = plc.y * m;
    const float t4 = tlc.x * m, t5 = tlc.y * m;

    const float x2v = p0 + p2, y2v = p1 + p3;
    const float areav = p2 * p3;
    const float cxe = p0 + 0.5f * p2, cye = p1 + 0.5f * p3;

    sA[i] = make_float4(p0, p1, x2v, y2v);
    sB[i] = make_float4(cxe, cye, areav, p4);
    sC[i] = make_float2(t4, m);
    __syncthreads();

    // ---------------- elementwise duty triple for this chunk ----------------
    float dA = 0.f, dB = 0.f, dC = 0.f;
    switch (chunk) {
    case 0: {
        // noise SmoothL1 (only chunk-0 blocks touch pn/tn)
        const float2* pn2 = (const float2*)pn;
        const float2* tn2 = (const float2*)tn;
        float noise = 0.f;
        #pragma unroll
        for (int k = 0; k < 3; ++k) {
            float2 a = pn2[r2 + k], bb = tn2[r2 + k];
            float d0 = fabsf(a.x * m - bb.x * m);
            float d1 = fabsf(a.y * m - bb.y * m);
            noise += (d0 < 1.f) ? 0.5f * d0 * d0 : d0 - 0.5f;
            noise += (d1 < 1.f) ? 0.5f * d1 * d1 : d1 - 0.5f;
        }
        dA = noise;
        // position MSE + IoU (needs target box rows)
        const float2 tla = tl2[r2 + 0], tlb = tl2[r2 + 1];
        const float t0 = tla.x * m, t1 = tla.y * m,
                    t2 = tlb.x * m, t3 = tlb.y * m;
        dB = (p0 - t0) * (p0 - t0) + (p1 - t1) * (p1 - t1)
           + (p2 - t2) * (p2 - t2) + (p3 - t3) * (p3 - t3);
        const float tx2 = t0 + t2, ty2 = t1 + t3;
        float iw = fmaxf(fminf(x2v, tx2) - fmaxf(p0, t0), 0.f);
        float ih = fmaxf(fminf(y2v, ty2) - fmaxf(p1, t1), 0.f);
        float inter = iw * ih;
        dC = 1.f - inter / (areav + t2 * t3 - inter + EPSF);
        break; }
    case 1:
        dA = (p4 - t4) * (p4 - t4);
        dB = (p5 - t5) * (p5 - t5);
        dC = fabsf(p2 / (p3 + EPSF) - 1.618f);
        break;
    case 2:
        dA = areav * m;
        dB = dA * dA;
        dC = cxe * m;
        break;
    default:
        dA = cye * m;
        dB = m;
        dC = 0.f;
        break;
    }

    // ---------------- pairwise terms (this chunk's 32-dd range) -------------
    float rank = 0.f, ovl = 0.f, aln = 0.f;
    const int dd0 = chunk * 32 + 1;
    #pragma unroll 8
    for (int k = 0; k < 32; ++k) {
        const int dd = dd0 + k;
        int j = (i + dd) & 255;
        if (dd == 128 && i >= 128) continue;   // dd=128 pairs counted once (i<j)
        float4 aj = sA[j];
        float4 bj = sB[j];
        float2 cj = sC[j];
        float pv = m * cj.y;
        // overlap (fast rcp: rel err ~1e-7, amortized over 2M pairs)
        float ow = fmaxf(fminf(x2v, aj.z) - fmaxf(p0, aj.x), 0.f);
        float oh = fmaxf(fminf(y2v, aj.w) - fmaxf(p1, aj.y), 0.f);
        ovl += ow * oh * pv * __builtin_amdgcn_rcpf(fminf(areav, bj.z) + EPSF);
        // alignment (6 edge types, dist<5 -> dist/5; /5 folded into 0.2f)
        float pen = 0.f, d;
        d = fabsf(p0  - aj.x); pen += (d < 5.f) ? d : 0.f;
        d = fabsf(x2v - aj.z); pen += (d < 5.f) ? d : 0.f;
        d = fabsf(p1  - aj.y); pen += (d < 5.f) ? d : 0.f;
        d = fabsf(y2v - aj.w); pen += (d < 5.f) ? d : 0.f;
        d = fabsf(cxe - bj.x); pen += (d < 5.f) ? d : 0.f;
        d = fabsf(cye - bj.y); pen += (d < 5.f) ? d : 0.f;
        aln += pen * (0.2f * pv);
        // ranking BCE, exact algebra: min( log1p(exp(-|z|)) + relu(z), 100 )
        bool ilt = (i < j);
        float dlo = ilt ? (bj.w - p4) : (p4 - bj.w);
        bool ylt  = ilt ? (t4 < cj.x) : (cj.x < t4);
        float z   = ylt ? -dlo : dlo;
        float sp  = __logf(1.f + __expf(-fabsf(z))) + fmaxf(z, 0.f);
        rank += fminf(sp, 100.f);
    }

    // one barrier pair for all six reductions
    float sr, so, sa, s1, s2, s3;
    block_sum6(rank, ovl, aln, dA, dB, dC, sred, sr, so, sa, s1, s2, s3);

    if (i == 0) {
        // publish partials as agent-scope write-through stores (no fence needed)
        float* pw = ws + PWBASE + blockIdx.x * 4;
        ws_cstore(pw + 0, sr);
        ws_cstore(pw + 1, so);
        ws_cstore(pw + 2, sa);
        // duty slots: chunk c writes slots {3c, 3c+1, 3c+2} (chunk 3: 9, 10 only)
        const int base = chunk * 3;
        ws_cstore(ws + PB(base + 0) + b, s1);
        ws_cstore(ws + PB(base + 1) + b, s2);
        if (chunk != 3) ws_cstore(ws + PB(base + 2) + b, s3);
        // all publishes retired -> globally visible (write-through)
        asm volatile("s_waitcnt vmcnt(0)" ::: "memory");
        // self-resetting hierarchical ticket (module globals, zero at load;
        // leaders reset so every iteration starts from 0 — no memset dispatch)
        int win = 0;
        const int g = blockIdx.x >> 5;
        unsigned gold = ctr_add(&g_group[g].v);
        if (gold == 31u) {
            ctr_reset(&g_group[g].v);
            unsigned mold = ctr_add(&g_master.v);
            if (mold == 7u) {
                ctr_reset(&g_master.v);
                win = 1;
            }
        }
        winflag = win;
    }
    __syncthreads();
    if (!winflag) return;

    // ================= winner block: final reduction =================
    const int t = i;

    // 256 packed pair-partials, one per thread (coherent reads)
    float v_rank, v_ovl, v_aln;
    {
        const float* p = ws + PWBASE + t * 4;
        v_rank = ws_cload(p + 0);
        v_ovl  = ws_cload(p + 1);
        v_aln  = ws_cload(p + 2);
    }
    float S_rank, S_ovl, S_aln;
    block_sum3(v_rank, v_ovl, v_aln, sred, S_rank, S_ovl, S_aln);

    if (t < 64) {
        float v_noise = ws_cload(ws + PB(0) + t);
        float v_pos   = ws_cload(ws + PB(1) + t);
        float v_iou   = ws_cload(ws + PB(2) + t);
        float v_lm    = ws_cload(ws + PB(3) + t);
        float v_cf    = ws_cload(ws + PB(4) + t);
        float v_go    = ws_cload(ws + PB(5) + t);
        float v_ar    = ws_cload(ws + PB(6) + t);
        float a2      = ws_cload(ws + PB(7) + t);
        float v_cx    = ws_cload(ws + PB(8) + t);
        float v_cy    = ws_cload(ws + PB(9) + t);
        float v_vc    = ws_cload(ws + PB(10) + t);
        // per-row std, ddof=1
        float var   = (a2 - v_ar * v_ar * (1.f / 256.f)) * (1.f / 255.f);
        float v_std = sqrtf(fmaxf(var, 0.f));

        // faithful [B,B] balance broadcast: ocx[i,j] = sumcx[j]/(vc[i]+EPS)
        float inv = 1.f / (v_vc + EPSF);
        float v_bal = 0.f;
        for (int j = 0; j < NB; ++j) {
            float cxj = __shfl(v_cx, j, 64);
            float cyj = __shfl(v_cy, j, 64);
            v_bal += fabsf(cxj * inv - 512.f) * (1.f / 512.f)
                   + fabsf(cyj * inv - 512.f) * (1.f / 512.f);
        }

        float S_noise = wave_sum(v_noise);
        float S_pos   = wave_sum(v_pos);
        float S_iou   = wave_sum(v_iou);
        float S_lm    = wave_sum(v_lm);
        float S_cf    = wave_sum(v_cf);
        float S_go    = wave_sum(v_go);
        float S_ar    = wave_sum(v_ar);
        float S_std   = wave_sum(v_std);
        float S_bal   = wave_sum(v_bal);

        if (t == 0) {
            const float BN = 64.f * 256.f;
            float noise_loss = S_noise / (BN * 6.f);
            float position   = S_pos / (BN * 4.f) + 0.5f * (S_iou / BN);
            float layer      = S_lm / BN + 0.3f * (S_rank / (64.f * NPAIRS));
            float conf       = S_cf / BN;
            float golden     = S_go / BN;
            float size_harm  = (S_std / 64.f) / (S_ar / BN + EPSF);
            float balance    = S_bal / 4096.f;
            float aes        = 0.1f * golden + 0.2f * size_harm + 0.15f * balance;
            float ovl        = S_ovl / (64.f * NPAIRS);
            float aln        = S_aln / (64.f * 6.f * NPAIRS);
            out[0] = noise_loss + position + 0.5f * layer + 0.3f * conf
                   + 0.2f * aes + 0.8f * ovl + 0.4f * aln;
        }
    }
}

extern "C" void kernel_launch(void* const* d_in, const int* in_sizes, int n_in,
                              void* d_out, int out_size, void* d_ws, size_t ws_size,
                              hipStream_t stream) {
    const float* pn   = (const float*)d_in[0];
    const float* tn   = (const float*)d_in[1];
    const float* pl   = (const float*)d_in[2];
    const float* tl   = (const float*)d_in[3];
    const float* mask = (const float*)d_in[4];
    float* ws  = (float*)d_ws;
    float* out = (float*)d_out;
    // single dispatch, no setup: tickets are self-resetting module globals
    hipLaunchKernelGGL(loss_fused, dim3(256), dim3(256), 0, stream,
                       pn, tn, pl, tl, mask, ws, out);
}